// Round 2
// baseline (3444.776 us; speedup 1.0000x reference)
//
#include <hip/hip_runtime.h>
#include <math.h>

#define Bn 16
#define Tn 16384
#define Fn 32
#define Cn 64
#define Ln 10

// ---------------------------------------------------------------------------
// Kernel 1: input 1x1 conv  h[b,c,t] = sum_f w_in[c,f]*x[b,t,f] + b_in[c]
// ---------------------------------------------------------------------------
__global__ __launch_bounds__(256) void k_input(const float* __restrict__ x,
                                               const float* __restrict__ w_in,
                                               const float* __restrict__ b_in,
                                               float* __restrict__ h)
{
    __shared__ float xs[64][33];   // +1 pad breaks bank conflicts on [tl][f] reads
    const int tid = threadIdx.x;
    const int b  = blockIdx.y;
    const int t0 = blockIdx.x * 64;

    const float* xp = x + ((size_t)b * Tn + t0) * Fn;
    #pragma unroll
    for (int i = 0; i < 8; ++i) {
        int e = i * 256 + tid;                 // e = tl*32 + f, coalesced
        xs[e >> 5][e & 31] = xp[e];
    }
    __syncthreads();

    const int tl = tid & 63;
    const int cb = (tid >> 6) * 16;
    float acc[16];
    #pragma unroll
    for (int c = 0; c < 16; ++c) acc[c] = 0.f;

    #pragma unroll 4
    for (int f = 0; f < 32; ++f) {
        const float xv = xs[tl][f];
        #pragma unroll
        for (int c = 0; c < 16; ++c)
            acc[c] = fmaf(w_in[(cb + c) * Fn + f], xv, acc[c]);  // uniform -> s_load
    }

    float* hp = h + ((size_t)b * Cn + cb) * Tn + t0 + tl;
    #pragma unroll
    for (int c = 0; c < 16; ++c)
        hp[(size_t)c * Tn] = acc[c] + b_in[cb + c];
}

// ---------------------------------------------------------------------------
// Kernel 2: one WaveNet layer, fused:
//   filt = tanh(conv3(h)), gate = sigmoid(conv3(h)), act = filt*gate
//   hout = (h + rw@act + rb) * 0.7071 ; skip = skip*scale + sw@act + sb
// Block: 256 threads, tile 64 co x 128 t; thread tile 8co x 4t.
// ---------------------------------------------------------------------------
// NOTE: macro param must NOT be named x/y/z/w — member tokens get substituted.
#define FMA4(A, cf, v) do {                   \
    A[0] = fmaf((cf), (v).x, A[0]);           \
    A[1] = fmaf((cf), (v).y, A[1]);           \
    A[2] = fmaf((cf), (v).z, A[2]);           \
    A[3] = fmaf((cf), (v).w, A[3]); } while (0)

__global__ __launch_bounds__(256, 2) void k_layer(
    const float* __restrict__ hin, float* __restrict__ hout,
    float* __restrict__ skip,
    const float* __restrict__ fw, const float* __restrict__ fb,
    const float* __restrict__ gw, const float* __restrict__ gb,
    const float* __restrict__ rw, const float* __restrict__ rb,
    const float* __restrict__ sw, const float* __restrict__ sb,
    const int dil, const float skip_scale)
{
    __shared__ float ht[Cn][128];   // h tap tile, later aliased as act tile (32KB)
    __shared__ float wA[Cn][Cn];    // wfT / rwT  transposed: [ci][co]  (16KB)
    __shared__ float wB[Cn][Cn];    // wgT / swT                        (16KB)

    const int tid = threadIdx.x;
    const int b   = blockIdx.y;
    const int t0  = blockIdx.x * 128;
    const int co0 = (tid & 7) * 8;        // 8 threads cover 64 co
    const int tl0 = (tid >> 3) * 4;       // 32 threads cover 128 t

    float af[8][4], ag[8][4], hkeep[8][4];
    #pragma unroll
    for (int i = 0; i < 8; ++i)
        #pragma unroll
        for (int j = 0; j < 4; ++j) { af[i][j] = 0.f; ag[i][j] = 0.f; }

    const float* hb = hin + (size_t)b * Cn * Tn;

    for (int tap = 0; tap < 3; ++tap) {
        const int off = (2 - tap) * dil;      // tap k reads h[t - (2-k)*d]
        __syncthreads();
        // stage h tile (zero-padded causal left edge), coalesced along t
        #pragma unroll
        for (int i = 0; i < 32; ++i) {
            int e  = i * 256 + tid;           // e = ci*128 + tc
            int ci = e >> 7, tc = e & 127;
            int tg = t0 + tc - off;
            ht[ci][tc] = (tg >= 0) ? hb[(size_t)ci * Tn + tg] : 0.f;
        }
        // stage transposed weights for this tap
        #pragma unroll
        for (int i = 0; i < 16; ++i) {
            int e  = i * 256 + tid;           // e = ci*64 + co
            int ci = e >> 6, co = e & 63;
            wA[ci][co] = fw[(co * Cn + ci) * 3 + tap];
            wB[ci][co] = gw[(co * Cn + ci) * 3 + tap];
        }
        __syncthreads();

        #pragma unroll 2
        for (int ci = 0; ci < 64; ++ci) {
            const float4 hv = *(const float4*)&ht[ci][tl0];
            const float4 f0 = *(const float4*)&wA[ci][co0];
            const float4 f1 = *(const float4*)&wA[ci][co0 + 4];
            const float4 g0 = *(const float4*)&wB[ci][co0];
            const float4 g1 = *(const float4*)&wB[ci][co0 + 4];
            FMA4(af[0], f0.x, hv); FMA4(af[1], f0.y, hv);
            FMA4(af[2], f0.z, hv); FMA4(af[3], f0.w, hv);
            FMA4(af[4], f1.x, hv); FMA4(af[5], f1.y, hv);
            FMA4(af[6], f1.z, hv); FMA4(af[7], f1.w, hv);
            FMA4(ag[0], g0.x, hv); FMA4(ag[1], g0.y, hv);
            FMA4(ag[2], g0.z, hv); FMA4(ag[3], g0.w, hv);
            FMA4(ag[4], g1.x, hv); FMA4(ag[5], g1.y, hv);
            FMA4(ag[6], g1.z, hv); FMA4(ag[7], g1.w, hv);
        }
        if (tap == 2) {
            // tap 2 has offset 0: keep this thread's h values for the residual add
            #pragma unroll
            for (int i = 0; i < 8; ++i) {
                const float4 hv = *(const float4*)&ht[co0 + i][tl0];
                hkeep[i][0] = hv.x; hkeep[i][1] = hv.y;
                hkeep[i][2] = hv.z; hkeep[i][3] = hv.w;
            }
        }
    }

    __syncthreads();
    // act = tanh(filt+fb) * sigmoid(gate+gb)  ->  LDS (alias of ht), layout [ci][t]
    #pragma unroll
    for (int i = 0; i < 8; ++i) {
        const int co = co0 + i;
        const float fbv = fb[co], gbv = gb[co];
        float4 av;
        av.x = tanhf(af[i][0] + fbv) / (1.f + expf(-(ag[i][0] + gbv)));
        av.y = tanhf(af[i][1] + fbv) / (1.f + expf(-(ag[i][1] + gbv)));
        av.z = tanhf(af[i][2] + fbv) / (1.f + expf(-(ag[i][2] + gbv)));
        av.w = tanhf(af[i][3] + fbv) / (1.f + expf(-(ag[i][3] + gbv)));
        *(float4*)&ht[co][tl0] = av;
    }
    // stage res/skip weights (transposed) into the weight regions
    #pragma unroll
    for (int i = 0; i < 16; ++i) {
        int e  = i * 256 + tid;
        int ci = e >> 6, co = e & 63;
        wA[ci][co] = rw[co * Cn + ci];
        wB[ci][co] = sw[co * Cn + ci];
    }
    __syncthreads();

    float ar[8][4], as_[8][4];
    #pragma unroll
    for (int i = 0; i < 8; ++i)
        #pragma unroll
        for (int j = 0; j < 4; ++j) { ar[i][j] = 0.f; as_[i][j] = 0.f; }

    #pragma unroll 2
    for (int ci = 0; ci < 64; ++ci) {
        const float4 av = *(const float4*)&ht[ci][tl0];
        const float4 r0 = *(const float4*)&wA[ci][co0];
        const float4 r1 = *(const float4*)&wA[ci][co0 + 4];
        const float4 s0 = *(const float4*)&wB[ci][co0];
        const float4 s1 = *(const float4*)&wB[ci][co0 + 4];
        FMA4(ar[0], r0.x, av); FMA4(ar[1], r0.y, av);
        FMA4(ar[2], r0.z, av); FMA4(ar[3], r0.w, av);
        FMA4(ar[4], r1.x, av); FMA4(ar[5], r1.y, av);
        FMA4(ar[6], r1.z, av); FMA4(ar[7], r1.w, av);
        FMA4(as_[0], s0.x, av); FMA4(as_[1], s0.y, av);
        FMA4(as_[2], s0.z, av); FMA4(as_[3], s0.w, av);
        FMA4(as_[4], s1.x, av); FMA4(as_[5], s1.y, av);
        FMA4(as_[6], s1.z, av); FMA4(as_[7], s1.w, av);
    }

    float* hob = hout + (size_t)b * Cn * Tn;
    float* skb = skip + (size_t)b * Cn * Tn;
    #pragma unroll
    for (int i = 0; i < 8; ++i) {
        const int co = co0 + i;
        const float rbv = rb[co], sbv = sb[co];
        const size_t base = (size_t)co * Tn + t0 + tl0;
        float4 ho;
        ho.x = (hkeep[i][0] + ar[i][0] + rbv) * 0.7071f;
        ho.y = (hkeep[i][1] + ar[i][1] + rbv) * 0.7071f;
        ho.z = (hkeep[i][2] + ar[i][2] + rbv) * 0.7071f;
        ho.w = (hkeep[i][3] + ar[i][3] + rbv) * 0.7071f;
        *(float4*)&hob[base] = ho;
        float4 so = *(const float4*)&skb[base];
        so.x = so.x * skip_scale + as_[i][0] + sbv;
        so.y = so.y * skip_scale + as_[i][1] + sbv;
        so.z = so.z * skip_scale + as_[i][2] + sbv;
        so.w = so.w * skip_scale + as_[i][3] + sbv;
        *(float4*)&skb[base] = so;
    }
}

// ---------------------------------------------------------------------------
// Kernel 3: output head  out[b,t] = ow2 @ relu(ow1 @ relu(skip) + ob1) + ob2
// ---------------------------------------------------------------------------
__global__ __launch_bounds__(256) void k_out(const float* __restrict__ skip,
                                             const float* __restrict__ ow1,
                                             const float* __restrict__ ob1,
                                             const float* __restrict__ ow2,
                                             const float* __restrict__ ob2,
                                             float* __restrict__ out)
{
    const int tid = threadIdx.x;
    const int b = blockIdx.y;
    const int t = blockIdx.x * 256 + tid;

    const float* sp = skip + (size_t)b * Cn * Tn + t;
    float y[64];
    #pragma unroll
    for (int c = 0; c < 64; ++c)
        y[c] = fmaxf(sp[(size_t)c * Tn], 0.f);

    float o = ob2[0];
    for (int co = 0; co < 64; ++co) {          // weights uniform -> scalar loads
        float a = ob1[co];
        #pragma unroll
        for (int ci = 0; ci < 64; ++ci)
            a = fmaf(ow1[co * 64 + ci], y[ci], a);
        o = fmaf(ow2[co], fmaxf(a, 0.f), o);
    }
    out[(size_t)b * Tn + t] = o;
}

// ---------------------------------------------------------------------------
extern "C" void kernel_launch(void* const* d_in, const int* in_sizes, int n_in,
                              void* d_out, int out_size, void* d_ws, size_t ws_size,
                              hipStream_t stream)
{
    const float* x    = (const float*)d_in[0];
    const float* w_in = (const float*)d_in[1];
    const float* b_in = (const float*)d_in[2];
    const float* fw   = (const float*)d_in[3];
    const float* fb   = (const float*)d_in[4];
    const float* gw   = (const float*)d_in[5];
    const float* gb   = (const float*)d_in[6];
    const float* rw   = (const float*)d_in[7];
    const float* rb   = (const float*)d_in[8];
    const float* sw   = (const float*)d_in[9];
    const float* sb   = (const float*)d_in[10];
    const float* ow1  = (const float*)d_in[11];
    const float* ob1  = (const float*)d_in[12];
    const float* ow2  = (const float*)d_in[13];
    const float* ob2  = (const float*)d_in[14];
    float* out = (float*)d_out;

    const size_t n = (size_t)Bn * Cn * Tn;     // 16.8M elems per tensor
    float* hA   = (float*)d_ws;                // ws layout: hA | hB | skip (192 MiB)
    float* hB   = hA + n;
    float* skip = hB + n;

    dim3 blk(256);
    k_input<<<dim3(Tn / 64, Bn), blk, 0, stream>>>(x, w_in, b_in, hA);

    const float* cur = hA;
    float* nxt = hB;
    for (int l = 0; l < Ln; ++l) {
        const int d = 1 << l;                  // dilations 1,2,...,512
        k_layer<<<dim3(Tn / 128, Bn), blk, 0, stream>>>(
            cur, nxt, skip,
            fw + (size_t)l * Cn * Cn * 3, fb + l * Cn,
            gw + (size_t)l * Cn * Cn * 3, gb + l * Cn,
            rw + (size_t)l * Cn * Cn,     rb + l * Cn,
            sw + (size_t)l * Cn * Cn,     sb + l * Cn,
            d, (l == 0) ? 0.f : 1.f);          // scale=0 absorbs 0xAA ws poison
        const float* tmp = nxt; nxt = (float*)cur; cur = tmp;
    }

    k_out<<<dim3(Tn / 256, Bn), blk, 0, stream>>>(skip, ow1, ob1, ow2, ob2, out);
}

// Round 3
// 940.050 us; speedup vs baseline: 3.6645x; 3.6645x over previous
//
#include <hip/hip_runtime.h>
#include <math.h>

#define Bn 16
#define Tn 16384
#define Fn 32
#define Cn 64
#define Ln 10

typedef _Float16 v8h  __attribute__((ext_vector_type(8)));
typedef _Float16 v4h  __attribute__((ext_vector_type(4)));
typedef float    v16f __attribute__((ext_vector_type(16)));
typedef float    v4f  __attribute__((ext_vector_type(4)));

// ---------------------------------------------------------------------------
// k_prep: pack weights fp32 -> fp16 in MFMA-friendly layouts.
// wfg16[l][row<128][k'<192]: row<64 -> fw[l][row][ci][tap] at k'=tap*64+ci,
//                            row>=64 -> gw (same k' layout)
// rs16 [l][row<128][ci<64] : row<64 -> rw[l][row][ci], row>=64 -> sw
// ---------------------------------------------------------------------------
__global__ __launch_bounds__(256) void k_prep(const float* __restrict__ fw,
                                              const float* __restrict__ gw,
                                              const float* __restrict__ rw,
                                              const float* __restrict__ sw,
                                              _Float16* __restrict__ wfg16,
                                              _Float16* __restrict__ rs16)
{
    int gid = blockIdx.x * 256 + threadIdx.x;
    if (gid < Ln * 128 * 192) {
        int l   = gid / (128 * 192);
        int rem = gid % (128 * 192);
        int row = rem / 192, k = rem % 192;
        int tap = k >> 6, ci = k & 63, co = row & 63;
        const float* wsrc = (row < 64) ? fw : gw;
        wfg16[gid] = (_Float16)wsrc[((l * 64 + co) * 64 + ci) * 3 + tap];
    }
    int gid2 = gid - Ln * 128 * 192;
    if (gid2 >= 0 && gid2 < Ln * 128 * 64) {
        int l   = gid2 / (128 * 64);
        int rem = gid2 % (128 * 64);
        int row = rem / 64, ci = rem & 63, co = row & 63;
        const float* wsrc = (row < 64) ? rw : sw;
        rs16[gid2] = (_Float16)wsrc[(l * 64 + co) * 64 + ci];
    }
}

// ---------------------------------------------------------------------------
// k_input: h[b][t][c] = fp16( sum_f w_in[c][f] * x[b][t][f] + b_in[c] )
// ---------------------------------------------------------------------------
__global__ __launch_bounds__(256) void k_input(const float* __restrict__ x,
                                               const float* __restrict__ w_in,
                                               const float* __restrict__ b_in,
                                               _Float16* __restrict__ h)
{
    const int t  = blockIdx.x * 256 + threadIdx.x;
    const int bb = blockIdx.y;
    const float* xp = x + ((size_t)bb * Tn + t) * Fn;
    float xv[32];
    #pragma unroll
    for (int i = 0; i < 8; ++i) {
        v4f v = *(const v4f*)&xp[i * 4];
        xv[i*4+0] = v[0]; xv[i*4+1] = v[1]; xv[i*4+2] = v[2]; xv[i*4+3] = v[3];
    }
    _Float16* hp = h + ((size_t)bb * Tn + t) * 64;
    #pragma unroll
    for (int c8 = 0; c8 < 8; ++c8) {
        v8h o;
        #pragma unroll
        for (int j = 0; j < 8; ++j) {
            int c = c8 * 8 + j;
            float a = b_in[c];
            #pragma unroll
            for (int f = 0; f < 32; ++f) a = fmaf(w_in[c * 32 + f], xv[f], a);
            o[j] = (_Float16)a;
        }
        *(v8h*)&hp[c8 * 8] = o;
    }
}

// ---------------------------------------------------------------------------
// k_layer: one WaveNet layer, all 4 GEMMs on MFMA (fp16 in, fp32 acc).
// Block 256 = 4 waves; block tile 64co x 128t; wave = (co-half wm, t-half wn),
// wave tile 32co x 64t for BOTH f and g (then both r and s).
// mfma_f32_32x32x16_f16: A[m=lane&31][k=(lane>>5)*8+j], B[k][n=lane&31],
// D: col(n)=lane&31, row(m)=(reg&3)+8*(reg>>2)+4*(lane>>5).
// ---------------------------------------------------------------------------
__global__ __launch_bounds__(256, 2) void k_layer(
    const _Float16* __restrict__ hin, _Float16* __restrict__ hout,
    float* __restrict__ skip,
    const _Float16* __restrict__ wfg,   // [128][192] this layer (f rows 0-63, g rows 64-127)
    const _Float16* __restrict__ rs,    // [128][64]  (r rows 0-63, s rows 64-127)
    const float* __restrict__ fb, const float* __restrict__ gb,
    const float* __restrict__ rb, const float* __restrict__ sb,
    const int dil, const float skip_scale)
{
    __shared__ _Float16 Ws[128 * 200];  // weights; stride 200 (taps) / 72 (rs reuse)
    __shared__ _Float16 Bt[128 * 72];   // h tap tile / act tile, [tl][k], stride 72

    const int tid  = threadIdx.x;
    const int lane = tid & 63;
    const int wv   = tid >> 6;
    const int wm   = wv & 1;            // co-half select
    const int wn   = wv >> 1;           // t-half select
    const int ch   = wm * 32;
    const int tb   = wn * 64;
    const int hl   = lane >> 5;
    const int ln31 = lane & 31;
    const int bb   = blockIdx.y;
    const int t0   = blockIdx.x * 128;

    v8h zero8;
    #pragma unroll
    for (int j = 0; j < 8; ++j) zero8[j] = (_Float16)0.f;

    // stage wf||wg [128][192] -> Ws (row stride 200 elems = 400B, 16B aligned)
    for (int i = tid; i < 3072; i += 256) {
        int row = i / 24, c = (i % 24) * 8;
        *(v8h*)&Ws[row * 200 + c] = *(const v8h*)&wfg[row * 192 + c];
    }

    v16f accF[2], accG[2];
    #pragma unroll
    for (int nt = 0; nt < 2; ++nt)
        #pragma unroll
        for (int j = 0; j < 16; ++j) { accF[nt][j] = 0.f; accG[nt][j] = 0.f; }

    const size_t hbase = (size_t)bb * Tn * 64;

    for (int tap = 0; tap < 3; ++tap) {
        const int off = (2 - tap) * dil;    // tap reads h[t - (2-tap)*d]
        if (tap) __syncthreads();           // prev K-loop reads done before overwrite
        for (int i = tid; i < 1024; i += 256) {
            int tl = i >> 3, c = (i & 7) * 8;
            int tg = t0 + tl - off;
            v8h v = zero8;
            if (tg >= 0) v = *(const v8h*)&hin[hbase + (size_t)tg * 64 + c];
            *(v8h*)&Bt[tl * 72 + c] = v;
        }
        __syncthreads();
        #pragma unroll
        for (int kc = 0; kc < 4; ++kc) {
            const int kof = kc * 16 + hl * 8;
            v8h aF = *(const v8h*)&Ws[(ch + ln31) * 200 + tap * 64 + kof];
            v8h aG = *(const v8h*)&Ws[(64 + ch + ln31) * 200 + tap * 64 + kof];
            v8h b0 = *(const v8h*)&Bt[(tb + ln31) * 72 + kof];
            v8h b1 = *(const v8h*)&Bt[(tb + 32 + ln31) * 72 + kof];
            accF[0] = __builtin_amdgcn_mfma_f32_32x32x16_f16(aF, b0, accF[0], 0, 0, 0);
            accF[1] = __builtin_amdgcn_mfma_f32_32x32x16_f16(aF, b1, accF[1], 0, 0, 0);
            accG[0] = __builtin_amdgcn_mfma_f32_32x32x16_f16(aG, b0, accG[0], 0, 0, 0);
            accG[1] = __builtin_amdgcn_mfma_f32_32x32x16_f16(aG, b1, accG[1], 0, 0, 0);
        }
    }
    __syncthreads();   // all reads of Ws(wfg) and Bt(tap2) complete

    // biases for this wave's co rows
    v4f fb4[4], gb4[4];
    #pragma unroll
    for (int q = 0; q < 4; ++q) {
        fb4[q] = *(const v4f*)&fb[ch + 8 * q + 4 * hl];
        gb4[q] = *(const v4f*)&gb[ch + 8 * q + 4 * hl];
    }

    // act = tanh(f+fb) * sigmoid(g+gb), written to Bt as [tl][ci] fp16
    #pragma unroll
    for (int nt = 0; nt < 2; ++nt) {
        const int tl = tb + nt * 32 + ln31;
        #pragma unroll
        for (int q = 0; q < 4; ++q)
            #pragma unroll
            for (int r = 0; r < 4; ++r) {
                float f = accF[nt][q * 4 + r] + fb4[q][r];
                float g = accG[nt][q * 4 + r] + gb4[q][r];
                float th = 1.f - 2.f / (__expf(2.f * f) + 1.f);   // tanh
                float sg = 1.f / (1.f + __expf(-g));              // sigmoid
                int ci = ch + 8 * q + 4 * hl + r;
                Bt[tl * 72 + ci] = (_Float16)(th * sg);
            }
    }

    // stage rw||sw [128][64] -> Ws (row stride 72)
    for (int i = tid; i < 1024; i += 256) {
        int row = i >> 3, c = (i & 7) * 8;
        *(v8h*)&Ws[row * 72 + c] = *(const v8h*)&rs[row * 64 + c];
    }
    __syncthreads();

    v16f accR[2], accS[2];
    #pragma unroll
    for (int nt = 0; nt < 2; ++nt)
        #pragma unroll
        for (int j = 0; j < 16; ++j) { accR[nt][j] = 0.f; accS[nt][j] = 0.f; }

    #pragma unroll
    for (int kc = 0; kc < 4; ++kc) {
        const int kof = kc * 16 + hl * 8;
        v8h aR = *(const v8h*)&Ws[(ch + ln31) * 72 + kof];
        v8h aS = *(const v8h*)&Ws[(64 + ch + ln31) * 72 + kof];
        v8h b0 = *(const v8h*)&Bt[(tb + ln31) * 72 + kof];
        v8h b1 = *(const v8h*)&Bt[(tb + 32 + ln31) * 72 + kof];
        accR[0] = __builtin_amdgcn_mfma_f32_32x32x16_f16(aR, b0, accR[0], 0, 0, 0);
        accR[1] = __builtin_amdgcn_mfma_f32_32x32x16_f16(aR, b1, accR[1], 0, 0, 0);
        accS[0] = __builtin_amdgcn_mfma_f32_32x32x16_f16(aS, b0, accS[0], 0, 0, 0);
        accS[1] = __builtin_amdgcn_mfma_f32_32x32x16_f16(aS, b1, accS[1], 0, 0, 0);
    }

    // epilogue: h_new = (h + res + rb)*0.7071 (fp16); skip RMW fp32
    v4f rb4[4], sb4[4];
    #pragma unroll
    for (int q = 0; q < 4; ++q) {
        rb4[q] = *(const v4f*)&rb[ch + 8 * q + 4 * hl];
        sb4[q] = *(const v4f*)&sb[ch + 8 * q + 4 * hl];
    }
    #pragma unroll
    for (int nt = 0; nt < 2; ++nt) {
        const int tg = t0 + tb + nt * 32 + ln31;
        #pragma unroll
        for (int q = 0; q < 4; ++q) {
            const int cb = ch + 8 * q + 4 * hl;
            const size_t base = hbase + (size_t)tg * 64 + cb;
            v4h hc = *(const v4h*)&hin[base];
            v4f sv = *(const v4f*)&skip[base];
            v4h hn;
            #pragma unroll
            for (int r = 0; r < 4; ++r) {
                hn[r] = (_Float16)(((float)hc[r] + accR[nt][q * 4 + r] + rb4[q][r]) * 0.7071f);
                sv[r] = sv[r] * skip_scale + accS[nt][q * 4 + r] + sb4[q][r];
            }
            *(v4h*)&hout[base] = hn;
            *(v4f*)&skip[base] = sv;
        }
    }
}

// ---------------------------------------------------------------------------
// k_out: out[b][t] = ow2 @ relu(ow1 @ relu(skip[b][t][:]) + ob1) + ob2
// ---------------------------------------------------------------------------
__global__ __launch_bounds__(256) void k_out(const float* __restrict__ skip,
                                             const float* __restrict__ ow1,
                                             const float* __restrict__ ob1,
                                             const float* __restrict__ ow2,
                                             const float* __restrict__ ob2,
                                             float* __restrict__ out)
{
    const int t  = blockIdx.x * 256 + threadIdx.x;
    const int bb = blockIdx.y;
    const float* sp = skip + ((size_t)bb * Tn + t) * 64;
    float y[64];
    #pragma unroll
    for (int i = 0; i < 16; ++i) {
        v4f v = *(const v4f*)&sp[i * 4];
        y[i*4+0] = fmaxf(v[0], 0.f); y[i*4+1] = fmaxf(v[1], 0.f);
        y[i*4+2] = fmaxf(v[2], 0.f); y[i*4+3] = fmaxf(v[3], 0.f);
    }
    float o = ob2[0];
    for (int co = 0; co < 64; ++co) {          // weights uniform -> s_loads
        float a0 = ob1[co], a1 = 0.f;
        #pragma unroll
        for (int ci = 0; ci < 64; ci += 2) {
            a0 = fmaf(ow1[co * 64 + ci],     y[ci],     a0);
            a1 = fmaf(ow1[co * 64 + ci + 1], y[ci + 1], a1);
        }
        o = fmaf(ow2[co], fmaxf(a0 + a1, 0.f), o);
    }
    out[(size_t)bb * Tn + t] = o;
}

// ---------------------------------------------------------------------------
extern "C" void kernel_launch(void* const* d_in, const int* in_sizes, int n_in,
                              void* d_out, int out_size, void* d_ws, size_t ws_size,
                              hipStream_t stream)
{
    const float* x    = (const float*)d_in[0];
    const float* w_in = (const float*)d_in[1];
    const float* b_in = (const float*)d_in[2];
    const float* fw   = (const float*)d_in[3];
    const float* fb   = (const float*)d_in[4];
    const float* gw   = (const float*)d_in[5];
    const float* gb   = (const float*)d_in[6];
    const float* rw   = (const float*)d_in[7];
    const float* rb   = (const float*)d_in[8];
    const float* sw   = (const float*)d_in[9];
    const float* sb   = (const float*)d_in[10];
    const float* ow1  = (const float*)d_in[11];
    const float* ob1  = (const float*)d_in[12];
    const float* ow2  = (const float*)d_in[13];
    const float* ob2  = (const float*)d_in[14];
    float* out = (float*)d_out;

    const size_t n = (size_t)Bn * Tn * 64;
    _Float16* hA    = (_Float16*)d_ws;
    _Float16* hB    = hA + n;
    float*    skip  = (float*)(hB + n);
    _Float16* wfg16 = (_Float16*)(skip + n);
    _Float16* rs16  = wfg16 + (size_t)Ln * 128 * 192;

    dim3 blk(256);
    k_prep<<<dim3((Ln * 128 * 192 + Ln * 128 * 64 + 255) / 256), blk, 0, stream>>>(
        fw, gw, rw, sw, wfg16, rs16);
    k_input<<<dim3(Tn / 256, Bn), blk, 0, stream>>>(x, w_in, b_in, hA);

    const _Float16* cur = hA;
    _Float16* nxt = hB;
    for (int l = 0; l < Ln; ++l) {
        const int d = 1 << l;                  // dilations 1..512
        k_layer<<<dim3(Tn / 128, Bn), blk, 0, stream>>>(
            cur, nxt, skip,
            wfg16 + (size_t)l * 128 * 192, rs16 + (size_t)l * 128 * 64,
            fb + l * Cn, gb + l * Cn, rb + l * Cn, sb + l * Cn,
            d, (l == 0) ? 0.f : 1.f);          // scale=0 absorbs 0xAA ws poison
        const _Float16* tmp = nxt; nxt = (_Float16*)cur; cur = tmp;
    }

    k_out<<<dim3(Tn / 256, Bn), blk, 0, stream>>>(skip, ow1, ob1, ow2, ob2, out);
}